// Round 1
// baseline (860.147 us; speedup 1.0000x reference)
//
#include <hip/hip_runtime.h>

// NNConv: out[n] = mean_{e: dst(e)=n} ( x[src(e)] @ reshape(relu(ea[e]@w1+b1)@w2+b2, 16,16) )
//                + x[n] @ root + bias
// N=50000, E=800000, IN=16, OUT=16, HID=32

#define N_NODES 50000
#define N_EDGES 800000
#define IN_D    16
#define OUT_D   16
#define HID_D   32

__device__ __forceinline__ void fma4(float a, const float4 w, float4& m) {
    m.x = fmaf(a, w.x, m.x);
    m.y = fmaf(a, w.y, m.y);
    m.z = fmaf(a, w.z, m.z);
    m.w = fmaf(a, w.w, m.w);
}

__global__ __launch_bounds__(256) void zero_ws(float4* __restrict__ ws, int n4) {
    int i = blockIdx.x * 256 + threadIdx.x;
    if (i < n4) ws[i] = make_float4(0.f, 0.f, 0.f, 0.f);
}

__global__ __launch_bounds__(256) void nnconv_edge(
    const float* __restrict__ x,
    const int*   __restrict__ ei,
    const float* __restrict__ ea,
    const float* __restrict__ w1,
    const float* __restrict__ b1,
    const float* __restrict__ w2,
    const float* __restrict__ b2,
    float* __restrict__ sums,
    float* __restrict__ cnt)
{
    // weights staged in LDS; all reads below are wave-uniform (broadcast) except s_xs
    __shared__ float4 s_w1[IN_D * HID_D / 4];          // [i][k4]   2 KB
    __shared__ float4 s_b1[HID_D / 4];                 //           128 B
    __shared__ float4 s_b2[IN_D * OUT_D / 4];          // [i][o4]   1 KB
    __shared__ float4 s_w2[HID_D * IN_D * OUT_D / 4];  // [k][i][o4] 32 KB
    __shared__ float  s_xs[IN_D * 256];                // [i][t]    16 KB (column-major: conflict-free)

    const int t = threadIdx.x;
    {
        const float4* w1v = reinterpret_cast<const float4*>(w1);
        const float4* b1v = reinterpret_cast<const float4*>(b1);
        const float4* b2v = reinterpret_cast<const float4*>(b2);
        const float4* w2v = reinterpret_cast<const float4*>(w2);
        if (t < IN_D * HID_D / 4) s_w1[t] = w1v[t];
        if (t < HID_D / 4)        s_b1[t] = b1v[t];
        if (t < IN_D * OUT_D / 4) s_b2[t] = b2v[t];
        for (int j = t; j < HID_D * IN_D * OUT_D / 4; j += 256) s_w2[j] = w2v[j];
    }
    __syncthreads();

    const int e = blockIdx.x * 256 + t;
    if (e >= N_EDGES) return;

    int src = ei[e];
    int dst = ei[N_EDGES + e];
    // defensive clamp: protects against index-dtype surprises (int64 vs int32)
    src = src < 0 ? 0 : (src >= N_NODES ? N_NODES - 1 : src);
    dst = dst < 0 ? 0 : (dst >= N_NODES ? N_NODES - 1 : dst);

    // ---- load edge_attr row (4x float4, fully cached-line utilized) ----
    float eav[IN_D];
    {
        const float4* eap = reinterpret_cast<const float4*>(ea) + (size_t)e * (IN_D / 4);
        float4 a0 = eap[0], a1 = eap[1], a2 = eap[2], a3 = eap[3];
        eav[0]=a0.x;  eav[1]=a0.y;  eav[2]=a0.z;  eav[3]=a0.w;
        eav[4]=a1.x;  eav[5]=a1.y;  eav[6]=a1.z;  eav[7]=a1.w;
        eav[8]=a2.x;  eav[9]=a2.y;  eav[10]=a2.z; eav[11]=a2.w;
        eav[12]=a3.x; eav[13]=a3.y; eav[14]=a3.z; eav[15]=a3.w;
    }

    // ---- stage x[src] into own LDS column (enables rolled i-loop below) ----
    {
        const float4* xp = reinterpret_cast<const float4*>(x) + (size_t)src * (IN_D / 4);
        float4 a0 = xp[0], a1 = xp[1], a2 = xp[2], a3 = xp[3];
        s_xs[ 0*256 + t] = a0.x; s_xs[ 1*256 + t] = a0.y; s_xs[ 2*256 + t] = a0.z; s_xs[ 3*256 + t] = a0.w;
        s_xs[ 4*256 + t] = a1.x; s_xs[ 5*256 + t] = a1.y; s_xs[ 6*256 + t] = a1.z; s_xs[ 7*256 + t] = a1.w;
        s_xs[ 8*256 + t] = a2.x; s_xs[ 9*256 + t] = a2.y; s_xs[10*256 + t] = a2.z; s_xs[11*256 + t] = a2.w;
        s_xs[12*256 + t] = a3.x; s_xs[13*256 + t] = a3.y; s_xs[14*256 + t] = a3.z; s_xs[15*256 + t] = a3.w;
    }

    // ---- h = relu(ea @ w1 + b1) : 512 FMA ----
    float4 hv[HID_D / 4];
    #pragma unroll
    for (int j = 0; j < HID_D / 4; ++j) hv[j] = s_b1[j];
    #pragma unroll
    for (int i = 0; i < IN_D; ++i) {
        const float xi = eav[i];
        #pragma unroll
        for (int j = 0; j < HID_D / 4; ++j) fma4(xi, s_w1[i * (HID_D / 4) + j], hv[j]);
    }
    float h[HID_D];
    #pragma unroll
    for (int j = 0; j < HID_D / 4; ++j) {
        h[4*j+0] = fmaxf(hv[j].x, 0.f);
        h[4*j+1] = fmaxf(hv[j].y, 0.f);
        h[4*j+2] = fmaxf(hv[j].z, 0.f);
        h[4*j+3] = fmaxf(hv[j].w, 0.f);
    }

    // ---- msg[o] = sum_i x_i * ( b2[i*16+o] + sum_k h_k * w2[k][i*16+o] ) ----
    // i-loop kept rolled (pragma unroll 1): body ~565 VALU instrs, fits I-cache;
    // xi comes from LDS column so no dynamic register indexing.
    float4 m0 = make_float4(0.f,0.f,0.f,0.f), m1 = m0, m2 = m0, m3 = m0;
    #pragma unroll 1
    for (int i = 0; i < IN_D; ++i) {
        const float xi = s_xs[i * 256 + t];
        const float4* bb = &s_b2[i * 4];
        fma4(xi, bb[0], m0); fma4(xi, bb[1], m1); fma4(xi, bb[2], m2); fma4(xi, bb[3], m3);
        #pragma unroll
        for (int k = 0; k < HID_D; ++k) {
            const float a = h[k] * xi;
            const float4* wr = &s_w2[(k * IN_D + i) * 4];
            fma4(a, wr[0], m0); fma4(a, wr[1], m1); fma4(a, wr[2], m2); fma4(a, wr[3], m3);
        }
    }

    // ---- scatter-add into per-node sums + degree count ----
    float* sp = sums + (size_t)dst * OUT_D;
    atomicAdd(sp + 0,  m0.x); atomicAdd(sp + 1,  m0.y); atomicAdd(sp + 2,  m0.z); atomicAdd(sp + 3,  m0.w);
    atomicAdd(sp + 4,  m1.x); atomicAdd(sp + 5,  m1.y); atomicAdd(sp + 6,  m1.z); atomicAdd(sp + 7,  m1.w);
    atomicAdd(sp + 8,  m2.x); atomicAdd(sp + 9,  m2.y); atomicAdd(sp + 10, m2.z); atomicAdd(sp + 11, m2.w);
    atomicAdd(sp + 12, m3.x); atomicAdd(sp + 13, m3.y); atomicAdd(sp + 14, m3.z); atomicAdd(sp + 15, m3.w);
    atomicAdd(cnt + dst, 1.0f);
}

__global__ __launch_bounds__(256) void nnconv_finalize(
    const float* __restrict__ x,
    const float* __restrict__ root,
    const float* __restrict__ bias,
    const float* __restrict__ sums,
    const float* __restrict__ cnt,
    float* __restrict__ out)
{
    __shared__ float4 s_root[IN_D * OUT_D / 4];  // [i][o4]
    __shared__ float4 s_bias[OUT_D / 4];
    const int t = threadIdx.x;
    if (t < IN_D * OUT_D / 4) s_root[t] = reinterpret_cast<const float4*>(root)[t];
    if (t < OUT_D / 4)        s_bias[t] = reinterpret_cast<const float4*>(bias)[t];
    __syncthreads();

    const int n = blockIdx.x * 256 + t;
    if (n >= N_NODES) return;

    float xs[IN_D];
    {
        const float4* xp = reinterpret_cast<const float4*>(x) + (size_t)n * (IN_D / 4);
        float4 a0 = xp[0], a1 = xp[1], a2 = xp[2], a3 = xp[3];
        xs[0]=a0.x;  xs[1]=a0.y;  xs[2]=a0.z;  xs[3]=a0.w;
        xs[4]=a1.x;  xs[5]=a1.y;  xs[6]=a1.z;  xs[7]=a1.w;
        xs[8]=a2.x;  xs[9]=a2.y;  xs[10]=a2.z; xs[11]=a2.w;
        xs[12]=a3.x; xs[13]=a3.y; xs[14]=a3.z; xs[15]=a3.w;
    }

    const float c   = cnt[n];
    const float inv = 1.0f / fmaxf(c, 1.0f);

    const float4* sp = reinterpret_cast<const float4*>(sums) + (size_t)n * (OUT_D / 4);
    float4 m0 = sp[0], m1 = sp[1], m2 = sp[2], m3 = sp[3];
    m0.x *= inv; m0.y *= inv; m0.z *= inv; m0.w *= inv;
    m1.x *= inv; m1.y *= inv; m1.z *= inv; m1.w *= inv;
    m2.x *= inv; m2.y *= inv; m2.z *= inv; m2.w *= inv;
    m3.x *= inv; m3.y *= inv; m3.z *= inv; m3.w *= inv;

    m0.x += s_bias[0].x; m0.y += s_bias[0].y; m0.z += s_bias[0].z; m0.w += s_bias[0].w;
    m1.x += s_bias[1].x; m1.y += s_bias[1].y; m1.z += s_bias[1].z; m1.w += s_bias[1].w;
    m2.x += s_bias[2].x; m2.y += s_bias[2].y; m2.z += s_bias[2].z; m2.w += s_bias[2].w;
    m3.x += s_bias[3].x; m3.y += s_bias[3].y; m3.z += s_bias[3].z; m3.w += s_bias[3].w;

    #pragma unroll
    for (int i = 0; i < IN_D; ++i) {
        const float xi = xs[i];
        fma4(xi, s_root[i*4+0], m0);
        fma4(xi, s_root[i*4+1], m1);
        fma4(xi, s_root[i*4+2], m2);
        fma4(xi, s_root[i*4+3], m3);
    }

    float4* op = reinterpret_cast<float4*>(out) + (size_t)n * (OUT_D / 4);
    op[0] = m0; op[1] = m1; op[2] = m2; op[3] = m3;
}

extern "C" void kernel_launch(void* const* d_in, const int* in_sizes, int n_in,
                              void* d_out, int out_size, void* d_ws, size_t ws_size,
                              hipStream_t stream) {
    const float* x    = (const float*)d_in[0];
    const int*   ei   = (const int*)  d_in[1];
    const float* ea   = (const float*)d_in[2];
    const float* w1   = (const float*)d_in[3];
    const float* b1   = (const float*)d_in[4];
    const float* w2   = (const float*)d_in[5];
    const float* b2   = (const float*)d_in[6];
    const float* root = (const float*)d_in[7];
    const float* bias = (const float*)d_in[8];

    float* out  = (float*)d_out;
    float* sums = (float*)d_ws;                       // N*16 floats
    float* cnt  = sums + (size_t)N_NODES * OUT_D;     // N floats

    const int n4 = (N_NODES * OUT_D + N_NODES) / 4;   // 212500 float4s, exact
    zero_ws<<<(n4 + 255) / 256, 256, 0, stream>>>((float4*)d_ws, n4);
    nnconv_edge<<<(N_EDGES + 255) / 256, 256, 0, stream>>>(x, ei, ea, w1, b1, w2, b2, sums, cnt);
    nnconv_finalize<<<(N_NODES + 255) / 256, 256, 0, stream>>>(x, root, bias, sums, cnt, out);
}

// Round 2
// 424.461 us; speedup vs baseline: 2.0264x; 2.0264x over previous
//
#include <hip/hip_runtime.h>

// NNConv via per-call CSR build + dst-sorted edge compute + LDS segmented
// reduction. R1 post-mortem: 13.6M device-scope fp32 atomics were the
// bottleneck (WRITE_SIZE 425MB, VALUBusy 14.5%). This version: ~100k fp32
// atomics (block-boundary runs only) + plain float4 stores for interior runs.
// N=50000, E=800000, IN=16, OUT=16, HID=32. E = 3125*256 exactly.

#define N_NODES 50000
#define N_EDGES 800000
#define IN_D    16
#define OUT_D   16
#define HID_D   32
#define NBLK_E  (N_EDGES / 256)          // 3125, exact
#define NBLK_N  ((N_NODES + 255) / 256)  // 196

__device__ __forceinline__ void fma4(float a, const float4 w, float4& m) {
    m.x = fmaf(a, w.x, m.x);
    m.y = fmaf(a, w.y, m.y);
    m.z = fmaf(a, w.z, m.z);
    m.w = fmaf(a, w.w, m.w);
}
__device__ __forceinline__ float4 add4(float4 a, float4 b) {
    return make_float4(a.x + b.x, a.y + b.y, a.z + b.z, a.w + b.w);
}
__device__ __forceinline__ int clampn(int v) {
    return v < 0 ? 0 : (v >= N_NODES ? N_NODES - 1 : v);
}

__global__ __launch_bounds__(256) void zero_ws(float4* __restrict__ ws, int n4) {
    int i = blockIdx.x * 256 + threadIdx.x;
    if (i < n4) ws[i] = make_float4(0.f, 0.f, 0.f, 0.f);
}

__global__ __launch_bounds__(256) void rank_k(const int* __restrict__ ei,
                                              int* __restrict__ deg,
                                              int* __restrict__ rank) {
    const int e = blockIdx.x * 256 + threadIdx.x;
    const int dst = clampn(ei[N_EDGES + e]);
    rank[e] = atomicAdd(&deg[dst], 1);
}

__global__ __launch_bounds__(256) void scan_a(const int* __restrict__ deg,
                                              int* __restrict__ loc,
                                              int* __restrict__ bsum) {
    __shared__ int s[256];
    const int t = threadIdx.x;
    const int i = blockIdx.x * 256 + t;
    const int v = (i < N_NODES) ? deg[i] : 0;
    s[t] = v;
    __syncthreads();
    #pragma unroll
    for (int d = 1; d < 256; d <<= 1) {
        int tmp = (t >= d) ? s[t - d] : 0;
        __syncthreads();
        s[t] += tmp;
        __syncthreads();
    }
    loc[i] = s[t] - v;
    if (t == 255) bsum[blockIdx.x] = s[255];
}

__global__ __launch_bounds__(256) void scan_b(const int* __restrict__ bsum,
                                              int* __restrict__ bofs) {
    __shared__ int s[256];
    const int t = threadIdx.x;
    const int v = (t < NBLK_N) ? bsum[t] : 0;
    s[t] = v;
    __syncthreads();
    #pragma unroll
    for (int d = 1; d < 256; d <<= 1) {
        int tmp = (t >= d) ? s[t - d] : 0;
        __syncthreads();
        s[t] += tmp;
        __syncthreads();
    }
    bofs[t] = s[t] - v;
}

__global__ __launch_bounds__(256) void scatter_k(const int* __restrict__ ei,
                                                 const int* __restrict__ loc,
                                                 const int* __restrict__ bofs,
                                                 const int* __restrict__ rank,
                                                 int* __restrict__ eids,
                                                 int* __restrict__ dsts) {
    const int e = blockIdx.x * 256 + threadIdx.x;
    const int dst = clampn(ei[N_EDGES + e]);
    const int slot = loc[dst] + bofs[dst >> 8] + rank[e];
    eids[slot] = e;
    dsts[slot] = dst;
}

__global__ __launch_bounds__(256) void nnconv_edge(
    const float* __restrict__ x,
    const int*   __restrict__ ei,
    const float* __restrict__ ea,
    const float* __restrict__ w1,
    const float* __restrict__ b1,
    const float* __restrict__ w2,
    const float* __restrict__ b2,
    const int*   __restrict__ eids,
    const int*   __restrict__ dsts,
    float* __restrict__ sums)
{
    __shared__ float4 s_w1[IN_D * HID_D / 4];          // 2 KB
    __shared__ float4 s_b1[HID_D / 4];                 // 128 B
    __shared__ float4 s_b2[IN_D * OUT_D / 4];          // 1 KB
    __shared__ float4 s_w2[HID_D * IN_D * OUT_D / 4];  // 32 KB
    __shared__ float4 s_buf4[IN_D * 256 / 4];          // 16 KB: x-cols, then msg rows
    __shared__ int    s_dst[256];
    float* s_buf = (float*)s_buf4;

    const int t = threadIdx.x;
    {
        const float4* w1v = reinterpret_cast<const float4*>(w1);
        const float4* b1v = reinterpret_cast<const float4*>(b1);
        const float4* b2v = reinterpret_cast<const float4*>(b2);
        const float4* w2v = reinterpret_cast<const float4*>(w2);
        if (t < IN_D * HID_D / 4) s_w1[t] = w1v[t];
        if (t < HID_D / 4)        s_b1[t] = b1v[t];
        if (t < IN_D * OUT_D / 4) s_b2[t] = b2v[t];
        for (int j = t; j < HID_D * IN_D * OUT_D / 4; j += 256) s_w2[j] = w2v[j];
    }

    const int g   = blockIdx.x * 256 + t;   // CSR position; grid exact, no guard
    const int e   = eids[g];
    const int dst = dsts[g];
    s_dst[t] = dst;
    const int src = clampn(ei[e]);

    float eav[IN_D];
    {
        const float4* eap = reinterpret_cast<const float4*>(ea) + (size_t)e * (IN_D / 4);
        float4 a0 = eap[0], a1 = eap[1], a2 = eap[2], a3 = eap[3];
        eav[0]=a0.x;  eav[1]=a0.y;  eav[2]=a0.z;  eav[3]=a0.w;
        eav[4]=a1.x;  eav[5]=a1.y;  eav[6]=a1.z;  eav[7]=a1.w;
        eav[8]=a2.x;  eav[9]=a2.y;  eav[10]=a2.z; eav[11]=a2.w;
        eav[12]=a3.x; eav[13]=a3.y; eav[14]=a3.z; eav[15]=a3.w;
    }
    {
        const float4* xp = reinterpret_cast<const float4*>(x) + (size_t)src * (IN_D / 4);
        float4 a0 = xp[0], a1 = xp[1], a2 = xp[2], a3 = xp[3];
        s_buf[ 0*256 + t] = a0.x; s_buf[ 1*256 + t] = a0.y; s_buf[ 2*256 + t] = a0.z; s_buf[ 3*256 + t] = a0.w;
        s_buf[ 4*256 + t] = a1.x; s_buf[ 5*256 + t] = a1.y; s_buf[ 6*256 + t] = a1.z; s_buf[ 7*256 + t] = a1.w;
        s_buf[ 8*256 + t] = a2.x; s_buf[ 9*256 + t] = a2.y; s_buf[10*256 + t] = a2.z; s_buf[11*256 + t] = a2.w;
        s_buf[12*256 + t] = a3.x; s_buf[13*256 + t] = a3.y; s_buf[14*256 + t] = a3.z; s_buf[15*256 + t] = a3.w;
    }
    __syncthreads();  // weights + s_dst staged (s_buf x-cols are self-only)

    float4 hv[HID_D / 4];
    #pragma unroll
    for (int j = 0; j < HID_D / 4; ++j) hv[j] = s_b1[j];
    #pragma unroll
    for (int i = 0; i < IN_D; ++i) {
        const float xi = eav[i];
        #pragma unroll
        for (int j = 0; j < HID_D / 4; ++j) fma4(xi, s_w1[i * (HID_D / 4) + j], hv[j]);
    }
    float h[HID_D];
    #pragma unroll
    for (int j = 0; j < HID_D / 4; ++j) {
        h[4*j+0] = fmaxf(hv[j].x, 0.f);
        h[4*j+1] = fmaxf(hv[j].y, 0.f);
        h[4*j+2] = fmaxf(hv[j].z, 0.f);
        h[4*j+3] = fmaxf(hv[j].w, 0.f);
    }

    float4 m0 = make_float4(0.f,0.f,0.f,0.f), m1 = m0, m2 = m0, m3 = m0;
    #pragma unroll 1
    for (int i = 0; i < IN_D; ++i) {
        const float xi = s_buf[i * 256 + t];
        const float4* bb = &s_b2[i * 4];
        fma4(xi, bb[0], m0); fma4(xi, bb[1], m1); fma4(xi, bb[2], m2); fma4(xi, bb[3], m3);
        #pragma unroll
        for (int k = 0; k < HID_D; ++k) {
            const float a = h[k] * xi;
            const float4* wr = &s_w2[(k * IN_D + i) * 4];
            fma4(a, wr[0], m0); fma4(a, wr[1], m1); fma4(a, wr[2], m2); fma4(a, wr[3], m3);
        }
    }

    // segmented reduction by dst (sorted within block)
    float4* sm4 = s_buf4;
    __syncthreads();  // all x-col self-reads done before overwrite as msg
    sm4[t*4+0] = m0; sm4[t*4+1] = m1; sm4[t*4+2] = m2; sm4[t*4+3] = m3;
    __syncthreads();

    const bool leader = (t == 0) || (s_dst[t-1] != dst);
    if (leader) {
        int end = t + 1;
        while (end < 256 && s_dst[end] == dst) ++end;
        float4 a0 = m0, a1 = m1, a2 = m2, a3 = m3;
        for (int j = t + 1; j < end; ++j) {
            const float4* p = &sm4[j*4];
            a0 = add4(a0, p[0]); a1 = add4(a1, p[1]);
            a2 = add4(a2, p[2]); a3 = add4(a3, p[3]);
        }
        float* sp = sums + (size_t)dst * OUT_D;
        if (t != 0 && end != 256) {
            float4* s4 = reinterpret_cast<float4*>(sp);
            s4[0] = a0; s4[1] = a1; s4[2] = a2; s4[3] = a3;
        } else {
            atomicAdd(sp + 0,  a0.x); atomicAdd(sp + 1,  a0.y); atomicAdd(sp + 2,  a0.z); atomicAdd(sp + 3,  a0.w);
            atomicAdd(sp + 4,  a1.x); atomicAdd(sp + 5,  a1.y); atomicAdd(sp + 6,  a1.z); atomicAdd(sp + 7,  a1.w);
            atomicAdd(sp + 8,  a2.x); atomicAdd(sp + 9,  a2.y); atomicAdd(sp + 10, a2.z); atomicAdd(sp + 11, a2.w);
            atomicAdd(sp + 12, a3.x); atomicAdd(sp + 13, a3.y); atomicAdd(sp + 14, a3.z); atomicAdd(sp + 15, a3.w);
        }
    }
}

__global__ __launch_bounds__(256) void nnconv_finalize(
    const float* __restrict__ x,
    const float* __restrict__ root,
    const float* __restrict__ bias,
    const float* __restrict__ sums,
    const int*   __restrict__ deg,
    float* __restrict__ out)
{
    __shared__ float4 s_root[IN_D * OUT_D / 4];
    __shared__ float4 s_bias[OUT_D / 4];
    const int t = threadIdx.x;
    if (t < IN_D * OUT_D / 4) s_root[t] = reinterpret_cast<const float4*>(root)[t];
    if (t < OUT_D / 4)        s_bias[t] = reinterpret_cast<const float4*>(bias)[t];
    __syncthreads();

    const int n = blockIdx.x * 256 + t;
    if (n >= N_NODES) return;

    float xs[IN_D];
    {
        const float4* xp = reinterpret_cast<const float4*>(x) + (size_t)n * (IN_D / 4);
        float4 a0 = xp[0], a1 = xp[1], a2 = xp[2], a3 = xp[3];
        xs[0]=a0.x;  xs[1]=a0.y;  xs[2]=a0.z;  xs[3]=a0.w;
        xs[4]=a1.x;  xs[5]=a1.y;  xs[6]=a1.z;  xs[7]=a1.w;
        xs[8]=a2.x;  xs[9]=a2.y;  xs[10]=a2.z; xs[11]=a2.w;
        xs[12]=a3.x; xs[13]=a3.y; xs[14]=a3.z; xs[15]=a3.w;
    }

    const int c = deg[n];
    const float inv = 1.0f / (float)(c > 1 ? c : 1);

    const float4* sp = reinterpret_cast<const float4*>(sums) + (size_t)n * (OUT_D / 4);
    float4 m0 = sp[0], m1 = sp[1], m2 = sp[2], m3 = sp[3];
    m0.x = m0.x*inv + s_bias[0].x; m0.y = m0.y*inv + s_bias[0].y; m0.z = m0.z*inv + s_bias[0].z; m0.w = m0.w*inv + s_bias[0].w;
    m1.x = m1.x*inv + s_bias[1].x; m1.y = m1.y*inv + s_bias[1].y; m1.z = m1.z*inv + s_bias[1].z; m1.w = m1.w*inv + s_bias[1].w;
    m2.x = m2.x*inv + s_bias[2].x; m2.y = m2.y*inv + s_bias[2].y; m2.z = m2.z*inv + s_bias[2].z; m2.w = m2.w*inv + s_bias[2].w;
    m3.x = m3.x*inv + s_bias[3].x; m3.y = m3.y*inv + s_bias[3].y; m3.z = m3.z*inv + s_bias[3].z; m3.w = m3.w*inv + s_bias[3].w;

    #pragma unroll
    for (int i = 0; i < IN_D; ++i) {
        const float xi = xs[i];
        fma4(xi, s_root[i*4+0], m0);
        fma4(xi, s_root[i*4+1], m1);
        fma4(xi, s_root[i*4+2], m2);
        fma4(xi, s_root[i*4+3], m3);
    }

    float4* op = reinterpret_cast<float4*>(out) + (size_t)n * (OUT_D / 4);
    op[0] = m0; op[1] = m1; op[2] = m2; op[3] = m3;
}

extern "C" void kernel_launch(void* const* d_in, const int* in_sizes, int n_in,
                              void* d_out, int out_size, void* d_ws, size_t ws_size,
                              hipStream_t stream) {
    const float* x    = (const float*)d_in[0];
    const int*   ei   = (const int*)  d_in[1];
    const float* ea   = (const float*)d_in[2];
    const float* w1   = (const float*)d_in[3];
    const float* b1   = (const float*)d_in[4];
    const float* w2   = (const float*)d_in[5];
    const float* b2   = (const float*)d_in[6];
    const float* root = (const float*)d_in[7];
    const float* bias = (const float*)d_in[8];
    float* out = (float*)d_out;

    // ws layout (13.2 MB)
    float* sums = (float*)d_ws;               // 800000 f32
    int*   deg  = (int*)(sums + N_EDGES);     // 50000
    int*   loc  = deg + N_NODES;              // 50176 (= NBLK_N*256)
    int*   bsum = loc + NBLK_N * 256;         // 196 (reuse tail of bofs region? keep separate)
    int*   bofs = bsum + 256;                 // 256
    int*   rank = bofs + 256;                 // 800000
    int*   eids = rank + N_EDGES;             // 800000
    int*   dsts = eids + N_EDGES;             // 800000

    const int n4 = (N_EDGES + N_NODES) / 4;   // zero sums+deg (contiguous)
    zero_ws  <<<(n4 + 255) / 256, 256, 0, stream>>>((float4*)d_ws, n4);
    rank_k   <<<NBLK_E, 256, 0, stream>>>(ei, deg, rank);
    scan_a   <<<NBLK_N, 256, 0, stream>>>(deg, loc, bsum);
    scan_b   <<<1,      256, 0, stream>>>(bsum, bofs);
    scatter_k<<<NBLK_E, 256, 0, stream>>>(ei, loc, bofs, rank, eids, dsts);
    nnconv_edge<<<NBLK_E, 256, 0, stream>>>(x, ei, ea, w1, b1, w2, b2, eids, dsts, sums);
    nnconv_finalize<<<NBLK_N, 256, 0, stream>>>(x, root, bias, sums, deg, out);
}

// Round 3
// 253.864 us; speedup vs baseline: 3.3882x; 1.6720x over previous
//
#include <hip/hip_runtime.h>
#include <hip/hip_bf16.h>

// NNConv, R3: edge compute reformulated as bf16 MFMA GEMM.
//   msg[E,16] = P[E,544] @ B[544,16],  P[e, k*16+i] = h[e,k] * x[src_e, i]
//   rows 512..527 of B = b2 (pseudo h=1, A elems = x_i), 528..543 = zero pad.
// A-frag per lane per K-tile = one h scalar * 8 resident x values -> 8 mul +
// 4 packed cvt; B staged once per block in LDS in B-fragment order.
// CSR build (rank/scan/scatter) + segmented reduction unchanged from R2.
// N=50000, E=800000, IN=16, OUT=16, HID=32. E = 3125*256 exactly.

#define N_NODES 50000
#define N_EDGES 800000
#define IN_D    16
#define OUT_D   16
#define HID_D   32
#define NBLK_E  (N_EDGES / 256)          // 3125, exact
#define NBLK_N  ((N_NODES + 255) / 256)  // 196
#define KTILES  17                        // 16 tiles of h*x + 1 tile for b2

typedef __attribute__((ext_vector_type(8))) short bfrag8;
typedef __attribute__((ext_vector_type(4))) float f32x4;

__device__ __forceinline__ void fma4(float a, const float4 w, float4& m) {
    m.x = fmaf(a, w.x, m.x);
    m.y = fmaf(a, w.y, m.y);
    m.z = fmaf(a, w.z, m.z);
    m.w = fmaf(a, w.w, m.w);
}
__device__ __forceinline__ int clampn(int v) {
    return v < 0 ? 0 : (v >= N_NODES ? N_NODES - 1 : v);
}
__device__ __forceinline__ bfrag8 pack8(const float* p) {
    union { bfrag8 v; __hip_bfloat162 h[4]; } u;
    u.h[0] = __float22bfloat162_rn(make_float2(p[0], p[1]));
    u.h[1] = __float22bfloat162_rn(make_float2(p[2], p[3]));
    u.h[2] = __float22bfloat162_rn(make_float2(p[4], p[5]));
    u.h[3] = __float22bfloat162_rn(make_float2(p[6], p[7]));
    return u.v;
}

__global__ __launch_bounds__(256) void zero_ws(float4* __restrict__ ws, int n4) {
    int i = blockIdx.x * 256 + threadIdx.x;
    if (i < n4) ws[i] = make_float4(0.f, 0.f, 0.f, 0.f);
}

__global__ __launch_bounds__(256) void rank_k(const int* __restrict__ ei,
                                              int* __restrict__ deg,
                                              int* __restrict__ rank) {
    const int e = blockIdx.x * 256 + threadIdx.x;
    const int dst = clampn(ei[N_EDGES + e]);
    rank[e] = atomicAdd(&deg[dst], 1);
}

__global__ __launch_bounds__(256) void scan_a(const int* __restrict__ deg,
                                              int* __restrict__ loc,
                                              int* __restrict__ bsum) {
    __shared__ int s[256];
    const int t = threadIdx.x;
    const int i = blockIdx.x * 256 + t;
    const int v = (i < N_NODES) ? deg[i] : 0;
    s[t] = v;
    __syncthreads();
    #pragma unroll
    for (int d = 1; d < 256; d <<= 1) {
        int tmp = (t >= d) ? s[t - d] : 0;
        __syncthreads();
        s[t] += tmp;
        __syncthreads();
    }
    loc[i] = s[t] - v;
    if (t == 255) bsum[blockIdx.x] = s[255];
}

__global__ __launch_bounds__(256) void scan_b(const int* __restrict__ bsum,
                                              int* __restrict__ bofs) {
    __shared__ int s[256];
    const int t = threadIdx.x;
    const int v = (t < NBLK_N) ? bsum[t] : 0;
    s[t] = v;
    __syncthreads();
    #pragma unroll
    for (int d = 1; d < 256; d <<= 1) {
        int tmp = (t >= d) ? s[t - d] : 0;
        __syncthreads();
        s[t] += tmp;
        __syncthreads();
    }
    bofs[t] = s[t] - v;
}

__global__ __launch_bounds__(256) void scatter_k(const int* __restrict__ ei,
                                                 const int* __restrict__ loc,
                                                 const int* __restrict__ bofs,
                                                 const int* __restrict__ rank,
                                                 int* __restrict__ eids,
                                                 int* __restrict__ dsts) {
    const int e = blockIdx.x * 256 + threadIdx.x;
    const int dst = clampn(ei[N_EDGES + e]);
    const int slot = loc[dst] + bofs[dst >> 8] + rank[e];
    eids[slot] = e;
    dsts[slot] = dst;
}

__global__ __launch_bounds__(256) void nnconv_edge(
    const float* __restrict__ x,
    const int*   __restrict__ ei,
    const float* __restrict__ ea,
    const float* __restrict__ w1,
    const float* __restrict__ b1,
    const float* __restrict__ w2,
    const float* __restrict__ b2,
    const int*   __restrict__ eids,
    const int*   __restrict__ dsts,
    float* __restrict__ sums)
{
    // LDS (~39 KB -> 4 blocks/CU):
    __shared__ bfrag8 s_B[KTILES * 64];      // 17408 B: B-frags, [tile][q][n] x 8 bf16
    __shared__ float  s_hm[256 * 17];        // 17408 B: h (bf16, [k][e]) then msg (f32, [e][o] stride 17)
    __shared__ float4 s_w1[IN_D * HID_D / 4];// 2 KB
    __shared__ float4 s_b1[HID_D / 4];       // 128 B
    __shared__ int    s_dst[256];
    __shared__ int    s_src[256];

    const int t = threadIdx.x;
    const int blockbase = blockIdx.x * 256;

    // ---- stage w1/b1 ----
    {
        const float4* w1v = reinterpret_cast<const float4*>(w1);
        const float4* b1v = reinterpret_cast<const float4*>(b1);
        if (t < IN_D * HID_D / 4) s_w1[t] = w1v[t];
        if (t < HID_D / 4)        s_b1[t] = b1v[t];
    }

    // ---- build B fragments in LDS: row r = k-index (0..543), col n = o ----
    // element index in bf16 units: ((tile*4+q)*16 + n)*8 + j,  r = tile*32+q*8+j
    {
        __hip_bfloat16* bp = reinterpret_cast<__hip_bfloat16*>(s_B);
        for (int r = t; r < KTILES * 32; r += 256) {
            const int tile = r >> 5, q = (r >> 3) & 3, j = r & 7;
            const int base = ((tile * 4 + q) * 16) * 8 + j;
            float vals[16];
            if (r < 512) {
                const float4* wr = reinterpret_cast<const float4*>(w2) + r * 4;
                float4 v0 = wr[0], v1 = wr[1], v2 = wr[2], v3 = wr[3];
                vals[0]=v0.x; vals[1]=v0.y; vals[2]=v0.z; vals[3]=v0.w;
                vals[4]=v1.x; vals[5]=v1.y; vals[6]=v1.z; vals[7]=v1.w;
                vals[8]=v2.x; vals[9]=v2.y; vals[10]=v2.z; vals[11]=v2.w;
                vals[12]=v3.x; vals[13]=v3.y; vals[14]=v3.z; vals[15]=v3.w;
            } else if (r < 528) {
                const float4* br = reinterpret_cast<const float4*>(b2) + (r - 512) * 4;
                float4 v0 = br[0], v1 = br[1], v2 = br[2], v3 = br[3];
                vals[0]=v0.x; vals[1]=v0.y; vals[2]=v0.z; vals[3]=v0.w;
                vals[4]=v1.x; vals[5]=v1.y; vals[6]=v1.z; vals[7]=v1.w;
                vals[8]=v2.x; vals[9]=v2.y; vals[10]=v2.z; vals[11]=v2.w;
                vals[12]=v3.x; vals[13]=v3.y; vals[14]=v3.z; vals[15]=v3.w;
            } else {
                #pragma unroll
                for (int o = 0; o < 16; ++o) vals[o] = 0.f;
            }
            #pragma unroll
            for (int o = 0; o < 16; ++o) bp[base + o * 8] = __float2bfloat16(vals[o]);
        }
    }

    // ---- per-thread: indices + edge MLP h, stored bf16 to s_hm[k][e] ----
    {
        const int g = blockbase + t;
        const int e = eids[g];
        s_dst[t] = dsts[g];
        s_src[t] = clampn(ei[e]);

        float eav[IN_D];
        {
            const float4* eap = reinterpret_cast<const float4*>(ea) + (size_t)e * 4;
            float4 a0 = eap[0], a1 = eap[1], a2 = eap[2], a3 = eap[3];
            eav[0]=a0.x;  eav[1]=a0.y;  eav[2]=a0.z;  eav[3]=a0.w;
            eav[4]=a1.x;  eav[5]=a1.y;  eav[6]=a1.z;  eav[7]=a1.w;
            eav[8]=a2.x;  eav[9]=a2.y;  eav[10]=a2.z; eav[11]=a2.w;
            eav[12]=a3.x; eav[13]=a3.y; eav[14]=a3.z; eav[15]=a3.w;
        }
        float4 hv[HID_D / 4];
        #pragma unroll
        for (int j = 0; j < HID_D / 4; ++j) hv[j] = s_b1[j];
        #pragma unroll
        for (int i = 0; i < IN_D; ++i) {
            const float xi = eav[i];
            #pragma unroll
            for (int j = 0; j < HID_D / 4; ++j) fma4(xi, s_w1[i * (HID_D / 4) + j], hv[j]);
        }
        __hip_bfloat16* s_h = reinterpret_cast<__hip_bfloat16*>(s_hm);
        #pragma unroll
        for (int j = 0; j < HID_D / 4; ++j) {
            s_h[(4*j+0)*256 + t] = __float2bfloat16(fmaxf(hv[j].x, 0.f));
            s_h[(4*j+1)*256 + t] = __float2bfloat16(fmaxf(hv[j].y, 0.f));
            s_h[(4*j+2)*256 + t] = __float2bfloat16(fmaxf(hv[j].z, 0.f));
            s_h[(4*j+3)*256 + t] = __float2bfloat16(fmaxf(hv[j].w, 0.f));
        }
    }
    __syncthreads();

    // ---- MFMA phase: each wave does 4 groups of 16 edges ----
    const __hip_bfloat16* s_h = reinterpret_cast<const __hip_bfloat16*>(s_hm);
    const int wbase = t & 192;          // wave*64
    const int q     = (t >> 4) & 3;     // quad within wave
    const int n     = t & 15;           // MFMA col (o) / row-in-group (m)
    const int qh    = q >> 1;           // k parity
    const int i0    = (q & 1) * 8;      // x sub-range for this quad

    f32x4 accs[4];
    #pragma unroll
    for (int sub = 0; sub < 4; ++sub) {
        const int posB = wbase + sub * 16 + n;   // position in block (edge row m = n here)
        const int src  = s_src[posB];
        float xr[8];
        {
            const float4* xp = reinterpret_cast<const float4*>(x) + (size_t)src * 4 + (i0 >> 2);
            float4 xa = xp[0], xb = xp[1];
            xr[0]=xa.x; xr[1]=xa.y; xr[2]=xa.z; xr[3]=xa.w;
            xr[4]=xb.x; xr[5]=xb.y; xr[6]=xb.z; xr[7]=xb.w;
        }
        f32x4 acc = {0.f, 0.f, 0.f, 0.f};
        #pragma unroll
        for (int tile = 0; tile < 16; ++tile) {
            const int k = 2 * tile + qh;
            const float hval = __bfloat162float(s_h[k * 256 + posB]);
            float p[8];
            #pragma unroll
            for (int j = 0; j < 8; ++j) p[j] = hval * xr[j];
            bfrag8 av = pack8(p);
            bfrag8 bv = s_B[tile * 64 + (t & 63)];
            acc = __builtin_amdgcn_mfma_f32_16x16x32_bf16(av, bv, acc, 0, 0, 0);
        }
        {   // b2 tile: rows 512..527 are x_i (pseudo h=1), 528..543 zero
            bfrag8 a16;
            if (qh == 0) a16 = pack8(xr);
            else { bfrag8 z = {0,0,0,0,0,0,0,0}; a16 = z; }
            bfrag8 bv = s_B[16 * 64 + (t & 63)];
            acc = __builtin_amdgcn_mfma_f32_16x16x32_bf16(a16, bv, acc, 0, 0, 0);
        }
        accs[sub] = acc;
    }
    __syncthreads();   // all s_h reads done; reuse s_hm as msg [e][o], stride 17

    #pragma unroll
    for (int sub = 0; sub < 4; ++sub) {
        #pragma unroll
        for (int r = 0; r < 4; ++r) {
            const int e = wbase + sub * 16 + q * 4 + r;   // C row m = q*4+r
            s_hm[e * 17 + n] = accs[sub][r];
        }
    }
    __syncthreads();

    // ---- segmented reduction by dst (sorted within block) ----
    const int dst = s_dst[t];
    const bool leader = (t == 0) || (s_dst[t - 1] != dst);
    if (leader) {
        int end = t + 1;
        while (end < 256 && s_dst[end] == dst) ++end;
        float a[16];
        #pragma unroll
        for (int o = 0; o < 16; ++o) a[o] = 0.f;
        for (int jrow = t; jrow < end; ++jrow) {
            const float* p = &s_hm[jrow * 17];
            #pragma unroll
            for (int o = 0; o < 16; ++o) a[o] += p[o];
        }
        float* sp = sums + (size_t)dst * OUT_D;
        if (t != 0 && end != 256) {
            #pragma unroll
            for (int o = 0; o < 16; ++o) sp[o] = a[o];
        } else {
            #pragma unroll
            for (int o = 0; o < 16; ++o) atomicAdd(sp + o, a[o]);
        }
    }
}

__global__ __launch_bounds__(256) void nnconv_finalize(
    const float* __restrict__ x,
    const float* __restrict__ root,
    const float* __restrict__ bias,
    const float* __restrict__ sums,
    const int*   __restrict__ deg,
    float* __restrict__ out)
{
    __shared__ float4 s_root[IN_D * OUT_D / 4];
    __shared__ float4 s_bias[OUT_D / 4];
    const int t = threadIdx.x;
    if (t < IN_D * OUT_D / 4) s_root[t] = reinterpret_cast<const float4*>(root)[t];
    if (t < OUT_D / 4)        s_bias[t] = reinterpret_cast<const float4*>(bias)[t];
    __syncthreads();

    const int n = blockIdx.x * 256 + t;
    if (n >= N_NODES) return;

    float xs[IN_D];
    {
        const float4* xp = reinterpret_cast<const float4*>(x) + (size_t)n * 4;
        float4 a0 = xp[0], a1 = xp[1], a2 = xp[2], a3 = xp[3];
        xs[0]=a0.x;  xs[1]=a0.y;  xs[2]=a0.z;  xs[3]=a0.w;
        xs[4]=a1.x;  xs[5]=a1.y;  xs[6]=a1.z;  xs[7]=a1.w;
        xs[8]=a2.x;  xs[9]=a2.y;  xs[10]=a2.z; xs[11]=a2.w;
        xs[12]=a3.x; xs[13]=a3.y; xs[14]=a3.z; xs[15]=a3.w;
    }

    const int c = deg[n];
    const float inv = 1.0f / (float)(c > 1 ? c : 1);

    const float4* sp = reinterpret_cast<const float4*>(sums) + (size_t)n * 4;
    float4 m0 = sp[0], m1 = sp[1], m2 = sp[2], m3 = sp[3];
    m0.x = m0.x*inv + s_bias[0].x; m0.y = m0.y*inv + s_bias[0].y; m0.z = m0.z*inv + s_bias[0].z; m0.w = m0.w*inv + s_bias[0].w;
    m1.x = m1.x*inv + s_bias[1].x; m1.y = m1.y*inv + s_bias[1].y; m1.z = m1.z*inv + s_bias[1].z; m1.w = m1.w*inv + s_bias[1].w;
    m2.x = m2.x*inv + s_bias[2].x; m2.y = m2.y*inv + s_bias[2].y; m2.z = m2.z*inv + s_bias[2].z; m2.w = m2.w*inv + s_bias[2].w;
    m3.x = m3.x*inv + s_bias[3].x; m3.y = m3.y*inv + s_bias[3].y; m3.z = m3.z*inv + s_bias[3].z; m3.w = m3.w*inv + s_bias[3].w;

    #pragma unroll
    for (int i = 0; i < IN_D; ++i) {
        const float xi = xs[i];
        fma4(xi, s_root[i*4+0], m0);
        fma4(xi, s_root[i*4+1], m1);
        fma4(xi, s_root[i*4+2], m2);
        fma4(xi, s_root[i*4+3], m3);
    }

    float4* op = reinterpret_cast<float4*>(out) + (size_t)n * 4;
    op[0] = m0; op[1] = m1; op[2] = m2; op[3] = m3;
}

extern "C" void kernel_launch(void* const* d_in, const int* in_sizes, int n_in,
                              void* d_out, int out_size, void* d_ws, size_t ws_size,
                              hipStream_t stream) {
    const float* x    = (const float*)d_in[0];
    const int*   ei   = (const int*)  d_in[1];
    const float* ea   = (const float*)d_in[2];
    const float* w1   = (const float*)d_in[3];
    const float* b1   = (const float*)d_in[4];
    const float* w2   = (const float*)d_in[5];
    const float* b2   = (const float*)d_in[6];
    const float* root = (const float*)d_in[7];
    const float* bias = (const float*)d_in[8];
    float* out = (float*)d_out;

    // ws layout (13.2 MB)
    float* sums = (float*)d_ws;               // 800000 f32
    int*   deg  = (int*)(sums + N_EDGES);     // 50000
    int*   loc  = deg + N_NODES;              // 50176 (= NBLK_N*256)
    int*   bsum = loc + NBLK_N * 256;         // 196 (padded region)
    int*   bofs = bsum + 256;                 // 256
    int*   rank = bofs + 256;                 // 800000
    int*   eids = rank + N_EDGES;             // 800000
    int*   dsts = eids + N_EDGES;             // 800000

    const int n4 = (N_EDGES + N_NODES) / 4;   // zero sums+deg (contiguous)
    zero_ws  <<<(n4 + 255) / 256, 256, 0, stream>>>((float4*)d_ws, n4);
    rank_k   <<<NBLK_E, 256, 0, stream>>>(ei, deg, rank);
    scan_a   <<<NBLK_N, 256, 0, stream>>>(deg, loc, bsum);
    scan_b   <<<1,      256, 0, stream>>>(bsum, bofs);
    scatter_k<<<NBLK_E, 256, 0, stream>>>(ei, loc, bofs, rank, eids, dsts);
    nnconv_edge<<<NBLK_E, 256, 0, stream>>>(x, ei, ea, w1, b1, w2, b2, eids, dsts, sums);
    nnconv_finalize<<<NBLK_N, 256, 0, stream>>>(x, root, bias, sums, deg, out);
}

// Round 6
// 230.470 us; speedup vs baseline: 3.7321x; 1.1015x over previous
//
#include <hip/hip_runtime.h>
#include <hip/hip_bf16.h>

// NNConv R6: ws-size-adaptive. R4/R5 post-mortem: we ignored ws_size; the
// scatter-msg paths needed 26/52 MB vs R3's proven 13.2 MB -> likely OOB
// writes corrupted adjacent allocations (moderate deterministic absmax).
// Also fixes a latent staging race (no barrier between s_w1/s_B staging and
// first use) present since R3. Host branches on ws_size (constant -> graph
// safe): big ws -> edge-order MFMA + cursor-scatter of fp32 msg rows + fused
// gather; small ws -> R3 CSR path (proven). N=50000, E=800000.

#define N_NODES 50000
#define N_EDGES 800000
#define IN_D    16
#define OUT_D   16
#define HID_D   32
#define NBLK_E  (N_EDGES / 256)          // 3125, exact
#define NBLK_N  ((N_NODES + 255) / 256)  // 196
#define KTILES  17                        // 16 tiles of h*x + 1 tile for b2

typedef __attribute__((ext_vector_type(8))) short bfrag8;
typedef __attribute__((ext_vector_type(4))) float f32x4;

__device__ __forceinline__ void fma4(float a, const float4 w, float4& m) {
    m.x = fmaf(a, w.x, m.x);
    m.y = fmaf(a, w.y, m.y);
    m.z = fmaf(a, w.z, m.z);
    m.w = fmaf(a, w.w, m.w);
}
__device__ __forceinline__ float4 add4(float4 a, float4 b) {
    return make_float4(a.x + b.x, a.y + b.y, a.z + b.z, a.w + b.w);
}
__device__ __forceinline__ int clampn(int v) {
    return v < 0 ? 0 : (v >= N_NODES ? N_NODES - 1 : v);
}
__device__ __forceinline__ bfrag8 pack8(const float* p) {
    union { bfrag8 v; __hip_bfloat162 h[4]; } u;
    u.h[0] = __float22bfloat162_rn(make_float2(p[0], p[1]));
    u.h[1] = __float22bfloat162_rn(make_float2(p[2], p[3]));
    u.h[2] = __float22bfloat162_rn(make_float2(p[4], p[5]));
    u.h[3] = __float22bfloat162_rn(make_float2(p[6], p[7]));
    return u.v;
}

// ---------------- shared scaffolding kernels ----------------

__global__ __launch_bounds__(256) void zero_k(int* __restrict__ p, int n) {
    const int i = blockIdx.x * 256 + threadIdx.x;
    if (i < n) p[i] = 0;
}

__global__ __launch_bounds__(256) void deg_k(const int* __restrict__ ei,
                                             int* __restrict__ deg) {
    const int e = blockIdx.x * 256 + threadIdx.x;
    atomicAdd(&deg[clampn(ei[N_EDGES + e])], 1);
}

__global__ __launch_bounds__(256) void rank_k(const int* __restrict__ ei,
                                              int* __restrict__ deg,
                                              int* __restrict__ rank) {
    const int e = blockIdx.x * 256 + threadIdx.x;
    rank[e] = atomicAdd(&deg[clampn(ei[N_EDGES + e])], 1);
}

__global__ __launch_bounds__(256) void scan_a(const int* __restrict__ deg,
                                              int* __restrict__ loc,
                                              int* __restrict__ bsum) {
    __shared__ int s[256];
    const int t = threadIdx.x;
    const int i = blockIdx.x * 256 + t;
    const int v = (i < N_NODES) ? deg[i] : 0;
    s[t] = v;
    __syncthreads();
    #pragma unroll
    for (int d = 1; d < 256; d <<= 1) {
        int tmp = (t >= d) ? s[t - d] : 0;
        __syncthreads();
        s[t] += tmp;
        __syncthreads();
    }
    loc[i] = s[t] - v;
    if (t == 255) bsum[blockIdx.x] = s[255];
}

__global__ __launch_bounds__(256) void scan_b(const int* __restrict__ bsum,
                                              int* __restrict__ bofs) {
    __shared__ int s[256];
    const int t = threadIdx.x;
    const int v = (t < NBLK_N) ? bsum[t] : 0;
    s[t] = v;
    __syncthreads();
    #pragma unroll
    for (int d = 1; d < 256; d <<= 1) {
        int tmp = (t >= d) ? s[t - d] : 0;
        __syncthreads();
        s[t] += tmp;
        __syncthreads();
    }
    bofs[t] = s[t] - v;
}

__global__ __launch_bounds__(256) void init_cursor(const int* __restrict__ loc,
                                                   const int* __restrict__ bofs,
                                                   int* __restrict__ cursor) {
    const int i = blockIdx.x * 256 + threadIdx.x;
    if (i < N_NODES) cursor[i] = loc[i] + bofs[i >> 8];
}

__global__ __launch_bounds__(256) void scatter_k(const int* __restrict__ ei,
                                                 const int* __restrict__ loc,
                                                 const int* __restrict__ bofs,
                                                 const int* __restrict__ rank,
                                                 int* __restrict__ eids,
                                                 int* __restrict__ dsts) {
    const int e = blockIdx.x * 256 + threadIdx.x;
    const int dst = clampn(ei[N_EDGES + e]);
    const int slot = loc[dst] + bofs[dst >> 8] + rank[e];
    eids[slot] = e;
    dsts[slot] = dst;
}

// ---------------- shared device helpers for edge compute ----------------

__device__ __forceinline__ void stage_weights(
    const float* __restrict__ w1, const float* __restrict__ b1,
    const float* __restrict__ w2, const float* __restrict__ b2,
    float4* s_w1, float4* s_b1, bfrag8* s_B, int t)
{
    const float4* w1v = reinterpret_cast<const float4*>(w1);
    const float4* b1v = reinterpret_cast<const float4*>(b1);
    if (t < IN_D * HID_D / 4) s_w1[t] = w1v[t];
    if (t < HID_D / 4)        s_b1[t] = b1v[t];

    __hip_bfloat16* bp = reinterpret_cast<__hip_bfloat16*>(s_B);
    for (int r = t; r < KTILES * 32; r += 256) {
        const int tile = r >> 5, q = (r >> 3) & 3, j = r & 7;
        const int base = ((tile * 4 + q) * 16) * 8 + j;
        float vals[16];
        if (r < 512) {
            const float4* wr = reinterpret_cast<const float4*>(w2) + r * 4;
            float4 v0 = wr[0], v1 = wr[1], v2 = wr[2], v3 = wr[3];
            vals[0]=v0.x; vals[1]=v0.y; vals[2]=v0.z; vals[3]=v0.w;
            vals[4]=v1.x; vals[5]=v1.y; vals[6]=v1.z; vals[7]=v1.w;
            vals[8]=v2.x; vals[9]=v2.y; vals[10]=v2.z; vals[11]=v2.w;
            vals[12]=v3.x; vals[13]=v3.y; vals[14]=v3.z; vals[15]=v3.w;
        } else if (r < 528) {
            const float4* br = reinterpret_cast<const float4*>(b2) + (r - 512) * 4;
            float4 v0 = br[0], v1 = br[1], v2 = br[2], v3 = br[3];
            vals[0]=v0.x; vals[1]=v0.y; vals[2]=v0.z; vals[3]=v0.w;
            vals[4]=v1.x; vals[5]=v1.y; vals[6]=v1.z; vals[7]=v1.w;
            vals[8]=v2.x; vals[9]=v2.y; vals[10]=v2.z; vals[11]=v2.w;
            vals[12]=v3.x; vals[13]=v3.y; vals[14]=v3.z; vals[15]=v3.w;
        } else {
            #pragma unroll
            for (int o = 0; o < 16; ++o) vals[o] = 0.f;
        }
        #pragma unroll
        for (int o = 0; o < 16; ++o) bp[base + o * 8] = __float2bfloat16(vals[o]);
    }
}

__device__ __forceinline__ void edge_mlp_to_lds(
    const float* __restrict__ ea, int e,
    const float4* s_w1, const float4* s_b1, float* s_hm, int t)
{
    float eav[IN_D];
    {
        const float4* eap = reinterpret_cast<const float4*>(ea) + (size_t)e * 4;
        float4 a0 = eap[0], a1 = eap[1], a2 = eap[2], a3 = eap[3];
        eav[0]=a0.x;  eav[1]=a0.y;  eav[2]=a0.z;  eav[3]=a0.w;
        eav[4]=a1.x;  eav[5]=a1.y;  eav[6]=a1.z;  eav[7]=a1.w;
        eav[8]=a2.x;  eav[9]=a2.y;  eav[10]=a2.z; eav[11]=a2.w;
        eav[12]=a3.x; eav[13]=a3.y; eav[14]=a3.z; eav[15]=a3.w;
    }
    float4 hv[HID_D / 4];
    #pragma unroll
    for (int j = 0; j < HID_D / 4; ++j) hv[j] = s_b1[j];
    #pragma unroll
    for (int i = 0; i < IN_D; ++i) {
        const float xi = eav[i];
        #pragma unroll
        for (int j = 0; j < HID_D / 4; ++j) fma4(xi, s_w1[i * (HID_D / 4) + j], hv[j]);
    }
    __hip_bfloat16* s_h = reinterpret_cast<__hip_bfloat16*>(s_hm);
    #pragma unroll
    for (int j = 0; j < HID_D / 4; ++j) {
        s_h[(4*j+0)*256 + t] = __float2bfloat16(fmaxf(hv[j].x, 0.f));
        s_h[(4*j+1)*256 + t] = __float2bfloat16(fmaxf(hv[j].y, 0.f));
        s_h[(4*j+2)*256 + t] = __float2bfloat16(fmaxf(hv[j].z, 0.f));
        s_h[(4*j+3)*256 + t] = __float2bfloat16(fmaxf(hv[j].w, 0.f));
    }
}

// MFMA phase: computes 4 C-fragments for this thread and writes the block's
// 256x16 msg matrix into s_hm rows (stride 17). Caller must sync before/after.
__device__ __forceinline__ void mfma_msgs(
    const float* __restrict__ x, const int* s_src,
    const float* s_hm_in, const bfrag8* s_B, int t, f32x4* accs)
{
    const __hip_bfloat16* s_h = reinterpret_cast<const __hip_bfloat16*>(s_hm_in);
    const int wbase = t & 192;
    const int q     = (t >> 4) & 3;
    const int n     = t & 15;
    const int qh    = q >> 1;
    const int i0    = (q & 1) * 8;

    #pragma unroll
    for (int sub = 0; sub < 4; ++sub) {
        const int posB = wbase + sub * 16 + n;
        const int srcB = s_src[posB];
        float xr[8];
        {
            const float4* xp = reinterpret_cast<const float4*>(x) + (size_t)srcB * 4 + (i0 >> 2);
            float4 xa = xp[0], xb = xp[1];
            xr[0]=xa.x; xr[1]=xa.y; xr[2]=xa.z; xr[3]=xa.w;
            xr[4]=xb.x; xr[5]=xb.y; xr[6]=xb.z; xr[7]=xb.w;
        }
        f32x4 acc = {0.f, 0.f, 0.f, 0.f};
        #pragma unroll
        for (int tile = 0; tile < 16; ++tile) {
            const int k = 2 * tile + qh;
            const float hval = __bfloat162float(s_h[k * 256 + posB]);
            float p[8];
            #pragma unroll
            for (int j = 0; j < 8; ++j) p[j] = hval * xr[j];
            bfrag8 av = pack8(p);
            bfrag8 bv = s_B[tile * 64 + (t & 63)];
            acc = __builtin_amdgcn_mfma_f32_16x16x32_bf16(av, bv, acc, 0, 0, 0);
        }
        {
            bfrag8 a16;
            if (qh == 0) a16 = pack8(xr);
            else { bfrag8 z = {0,0,0,0,0,0,0,0}; a16 = z; }
            bfrag8 bv = s_B[16 * 64 + (t & 63)];
            acc = __builtin_amdgcn_mfma_f32_16x16x32_bf16(a16, bv, acc, 0, 0, 0);
        }
        accs[sub] = acc;
    }
}

__device__ __forceinline__ void write_cfrags(float* s_hm, const f32x4* accs, int t) {
    const int wbase = t & 192;
    const int q     = (t >> 4) & 3;
    const int n     = t & 15;
    #pragma unroll
    for (int sub = 0; sub < 4; ++sub) {
        #pragma unroll
        for (int r = 0; r < 4; ++r) {
            const int er = wbase + sub * 16 + q * 4 + r;
            s_hm[er * 17 + n] = accs[sub][r];
        }
    }
}

// ---------------- BIG-WS PATH: edge-order compute + cursor scatter ----------------

__global__ __launch_bounds__(256) void edge_scatter(
    const float* __restrict__ x,
    const int*   __restrict__ ei,
    const float* __restrict__ ea,
    const float* __restrict__ w1,
    const float* __restrict__ b1,
    const float* __restrict__ w2,
    const float* __restrict__ b2,
    int*   __restrict__ cursor,
    float* __restrict__ msg)
{
    __shared__ bfrag8 s_B[KTILES * 64];
    __shared__ float  s_hm[256 * 17];
    __shared__ float4 s_w1[IN_D * HID_D / 4];
    __shared__ float4 s_b1[HID_D / 4];
    __shared__ int    s_src[256];

    const int t = threadIdx.x;
    const int e = blockIdx.x * 256 + t;   // original edge order, grid exact

    const int src = clampn(ei[e]);
    const int dst = clampn(ei[N_EDGES + e]);
    const int slot = atomicAdd(&cursor[dst], 1);
    s_src[t] = src;

    stage_weights(w1, b1, w2, b2, s_w1, s_b1, s_B, t);
    __syncthreads();                       // staging visible (race fix)

    edge_mlp_to_lds(ea, e, s_w1, s_b1, s_hm, t);
    __syncthreads();                       // h visible

    f32x4 accs[4];
    mfma_msgs(x, s_src, s_hm, s_B, t, accs);
    __syncthreads();                       // all s_h reads done
    write_cfrags(s_hm, accs, t);
    __syncthreads();                       // msg rows visible

    const float* p = &s_hm[t * 17];
    float4* mp = reinterpret_cast<float4*>(msg + (size_t)slot * 16);
    mp[0] = make_float4(p[0],  p[1],  p[2],  p[3]);
    mp[1] = make_float4(p[4],  p[5],  p[6],  p[7]);
    mp[2] = make_float4(p[8],  p[9],  p[10], p[11]);
    mp[3] = make_float4(p[12], p[13], p[14], p[15]);
}

__global__ __launch_bounds__(256) void gather_finalize(
    const float* __restrict__ x,
    const float* __restrict__ root,
    const float* __restrict__ bias,
    const float* __restrict__ msg,
    const int*   __restrict__ cursor,   // post-edge: segment END
    const int*   __restrict__ deg,
    float* __restrict__ out)
{
    __shared__ float4 s_root[IN_D * OUT_D / 4];
    __shared__ float4 s_bias[OUT_D / 4];
    const int t = threadIdx.x;
    if (t < IN_D * OUT_D / 4) s_root[t] = reinterpret_cast<const float4*>(root)[t];
    if (t < OUT_D / 4)        s_bias[t] = reinterpret_cast<const float4*>(bias)[t];
    __syncthreads();

    const int n = blockIdx.x * 256 + t;
    if (n >= N_NODES) return;

    const int d   = deg[n];
    const int end = cursor[n];
    const int j0  = end - d;

    float4 a0 = make_float4(0.f,0.f,0.f,0.f), a1 = a0, a2 = a0, a3 = a0;
    for (int j = j0; j < end; ++j) {
        const float4* mp = reinterpret_cast<const float4*>(msg + (size_t)j * 16);
        a0 = add4(a0, mp[0]); a1 = add4(a1, mp[1]);
        a2 = add4(a2, mp[2]); a3 = add4(a3, mp[3]);
    }

    const float inv = 1.0f / (float)(d > 1 ? d : 1);
    float4 m0 = make_float4(a0.x*inv + s_bias[0].x, a0.y*inv + s_bias[0].y,
                            a0.z*inv + s_bias[0].z, a0.w*inv + s_bias[0].w);
    float4 m1 = make_float4(a1.x*inv + s_bias[1].x, a1.y*inv + s_bias[1].y,
                            a1.z*inv + s_bias[1].z, a1.w*inv + s_bias[1].w);
    float4 m2 = make_float4(a2.x*inv + s_bias[2].x, a2.y*inv + s_bias[2].y,
                            a2.z*inv + s_bias[2].z, a2.w*inv + s_bias[2].w);
    float4 m3 = make_float4(a3.x*inv + s_bias[3].x, a3.y*inv + s_bias[3].y,
                            a3.z*inv + s_bias[3].z, a3.w*inv + s_bias[3].w);

    float xs[IN_D];
    {
        const float4* xp = reinterpret_cast<const float4*>(x) + (size_t)n * 4;
        float4 b0 = xp[0], b1v = xp[1], b2v = xp[2], b3 = xp[3];
        xs[0]=b0.x;  xs[1]=b0.y;  xs[2]=b0.z;  xs[3]=b0.w;
        xs[4]=b1v.x; xs[5]=b1v.y; xs[6]=b1v.z; xs[7]=b1v.w;
        xs[8]=b2v.x; xs[9]=b2v.y; xs[10]=b2v.z; xs[11]=b2v.w;
        xs[12]=b3.x; xs[13]=b3.y; xs[14]=b3.z; xs[15]=b3.w;
    }
    #pragma unroll
    for (int i = 0; i < IN_D; ++i) {
        const float xi = xs[i];
        fma4(xi, s_root[i*4+0], m0);
        fma4(xi, s_root[i*4+1], m1);
        fma4(xi, s_root[i*4+2], m2);
        fma4(xi, s_root[i*4+3], m3);
    }

    float4* op = reinterpret_cast<float4*>(out) + (size_t)n * 4;
    op[0] = m0; op[1] = m1; op[2] = m2; op[3] = m3;
}

// ---------------- SMALL-WS PATH: R3 CSR + in-block segmented reduction ----------------

__global__ __launch_bounds__(256) void edge_csr(
    const float* __restrict__ x,
    const int*   __restrict__ ei,
    const float* __restrict__ ea,
    const float* __restrict__ w1,
    const float* __restrict__ b1,
    const float* __restrict__ w2,
    const float* __restrict__ b2,
    const int*   __restrict__ eids,
    const int*   __restrict__ dsts,
    float* __restrict__ sums)
{
    __shared__ bfrag8 s_B[KTILES * 64];
    __shared__ float  s_hm[256 * 17];
    __shared__ float4 s_w1[IN_D * HID_D / 4];
    __shared__ float4 s_b1[HID_D / 4];
    __shared__ int    s_dst[256];
    __shared__ int    s_src[256];

    const int t = threadIdx.x;
    const int g = blockIdx.x * 256 + t;   // CSR position, grid exact
    const int e = eids[g];
    const int dst = dsts[g];
    s_dst[t] = dst;
    s_src[t] = clampn(ei[e]);

    stage_weights(w1, b1, w2, b2, s_w1, s_b1, s_B, t);
    __syncthreads();                       // staging visible (race fix)

    edge_mlp_to_lds(ea, e, s_w1, s_b1, s_hm, t);
    __syncthreads();                       // h visible

    f32x4 accs[4];
    mfma_msgs(x, s_src, s_hm, s_B, t, accs);
    __syncthreads();
    write_cfrags(s_hm, accs, t);
    __syncthreads();

    const bool leader = (t == 0) || (s_dst[t - 1] != dst);
    if (leader) {
        int end = t + 1;
        while (end < 256 && s_dst[end] == dst) ++end;
        float a[16];
        #pragma unroll
        for (int o = 0; o < 16; ++o) a[o] = 0.f;
        for (int jrow = t; jrow < end; ++jrow) {
            const float* p = &s_hm[jrow * 17];
            #pragma unroll
            for (int o = 0; o < 16; ++o) a[o] += p[o];
        }
        float* sp = sums + (size_t)dst * OUT_D;
        if (t != 0 && end != 256) {
            float4* s4 = reinterpret_cast<float4*>(sp);
            s4[0] = make_float4(a[0], a[1], a[2], a[3]);
            s4[1] = make_float4(a[4], a[5], a[6], a[7]);
            s4[2] = make_float4(a[8], a[9], a[10], a[11]);
            s4[3] = make_float4(a[12], a[13], a[14], a[15]);
        } else {
            #pragma unroll
            for (int o = 0; o < 16; ++o) atomicAdd(sp + o, a[o]);
        }
    }
}

__global__ __launch_bounds__(256) void finalize_sums(
    const float* __restrict__ x,
    const float* __restrict__ root,
    const float* __restrict__ bias,
    const float* __restrict__ sums,
    const int*   __restrict__ deg,
    float* __restrict__ out)
{
    __shared__ float4 s_root[IN_D * OUT_D / 4];
    __shared__ float4 s_bias[OUT_D / 4];
    const int t = threadIdx.x;
    if (t < IN_D * OUT_D / 4) s_root[t] = reinterpret_cast<const float4*>(root)[t];
    if (t < OUT_D / 4)        s_bias[t] = reinterpret_cast<const float4*>(bias)[t];
    __syncthreads();

    const int n = blockIdx.x * 256 + t;
    if (n >= N_NODES) return;

    const int c = deg[n];
    const float inv = 1.0f / (float)(c > 1 ? c : 1);

    const float4* sp = reinterpret_cast<const float4*>(sums) + (size_t)n * 4;
    float4 m0 = sp[0], m1 = sp[1], m2 = sp[2], m3 = sp[3];
    m0.x = m0.x*inv + s_bias[0].x; m0.y = m0.y*inv + s_bias[0].y; m0.z = m0.z*inv + s_bias[0].z; m0.w = m0.w*inv + s_bias[0].w;
    m1.x = m1.x*inv + s_bias[1].x; m1.y = m1.y*inv + s_bias[1].y; m1.z = m1.z*inv + s_bias[1].z; m1.w = m1.w*inv + s_bias[1].w;
    m2.x = m2.x*inv + s_bias[2].x; m2.y = m2.y*inv + s_bias[2].y; m2.z = m2.z*inv + s_bias[2].z; m2.w = m2.w*inv + s_bias[2].w;
    m3.x = m3.x*inv + s_bias[3].x; m3.y = m3.y*inv + s_bias[3].y; m3.z = m3.z*inv + s_bias[3].z; m3.w = m3.w*inv + s_bias[3].w;

    float xs[IN_D];
    {
        const float4* xp = reinterpret_cast<const float4*>(x) + (size_t)n * 4;
        float4 a0 = xp[0], a1 = xp[1], a2 = xp[2], a3 = xp[3];
        xs[0]=a0.x;  xs[1]=a0.y;  xs[2]=a0.z;  xs[3]=a0.w;
        xs[4]=a1.x;  xs[5]=a1.y;  xs[6]=a1.z;  xs[7]=a1.w;
        xs[8]=a2.x;  xs[9]=a2.y;  xs[10]=a2.z; xs[11]=a2.w;
        xs[12]=a3.x; xs[13]=a3.y; xs[14]=a3.z; xs[15]=a3.w;
    }
    #pragma unroll
    for (int i = 0; i < IN_D; ++i) {
        const float xi = xs[i];
        fma4(xi, s_root[i*4+0], m0);
        fma4(xi, s_root[i*4+1], m1);
        fma4(xi, s_root[i*4+2], m2);
        fma4(xi, s_root[i*4+3], m3);
    }

    float4* op = reinterpret_cast<float4*>(out) + (size_t)n * 4;
    op[0] = m0; op[1] = m1; op[2] = m2; op[3] = m3;
}

extern "C" void kernel_launch(void* const* d_in, const int* in_sizes, int n_in,
                              void* d_out, int out_size, void* d_ws, size_t ws_size,
                              hipStream_t stream) {
    const float* x    = (const float*)d_in[0];
    const int*   ei   = (const int*)  d_in[1];
    const float* ea   = (const float*)d_in[2];
    const float* w1   = (const float*)d_in[3];
    const float* b1   = (const float*)d_in[4];
    const float* w2   = (const float*)d_in[5];
    const float* b2   = (const float*)d_in[6];
    const float* root = (const float*)d_in[7];
    const float* bias = (const float*)d_in[8];
    float* out = (float*)d_out;

    // big path needs: hdr (deg,loc,bsum,bofs,cursor = 150688 ints) + msg E*16 f32
    const size_t need_big = (size_t)(N_NODES + NBLK_N * 256 + 256 + 256 + N_NODES) * 4
                          + (size_t)N_EDGES * 16 * 4;

    if (ws_size >= need_big) {
        // ---- big-ws path (~51.8 MB) ----
        int* deg    = (int*)d_ws;                 // 50000
        int* loc    = deg + N_NODES;              // 50176
        int* bsum   = loc + NBLK_N * 256;         // 256 (196 used)
        int* bofs   = bsum + 256;                 // 256
        int* cursor = bofs + 256;                 // 50000
        float* msg  = (float*)(cursor + N_NODES); // E*16 f32

        zero_k     <<<(N_NODES + 255) / 256, 256, 0, stream>>>(deg, N_NODES);
        deg_k      <<<NBLK_E, 256, 0, stream>>>(ei, deg);
        scan_a     <<<NBLK_N, 256, 0, stream>>>(deg, loc, bsum);
        scan_b     <<<1,      256, 0, stream>>>(bsum, bofs);
        init_cursor<<<NBLK_N, 256, 0, stream>>>(loc, bofs, cursor);
        edge_scatter<<<NBLK_E, 256, 0, stream>>>(x, ei, ea, w1, b1, w2, b2, cursor, msg);
        gather_finalize<<<NBLK_N, 256, 0, stream>>>(x, root, bias, msg, cursor, deg, out);
    } else {
        // ---- small-ws fallback (R3 layout, 13.2 MB, proven) ----
        float* sums = (float*)d_ws;               // 800000 f32
        int*   deg  = (int*)(sums + N_EDGES);     // 50000
        int*   loc  = deg + N_NODES;              // 50176
        int*   bsum = loc + NBLK_N * 256;         // 256 (196 used)
        int*   bofs = bsum + 256;                 // 256
        int*   rank = bofs + 256;                 // 800000
        int*   eids = rank + N_EDGES;             // 800000
        int*   dsts = eids + N_EDGES;             // 800000

        zero_k   <<<(N_EDGES + N_NODES + 255) / 256, 256, 0, stream>>>((int*)d_ws, N_EDGES + N_NODES);
        rank_k   <<<NBLK_E, 256, 0, stream>>>(ei, deg, rank);
        scan_a   <<<NBLK_N, 256, 0, stream>>>(deg, loc, bsum);
        scan_b   <<<1,      256, 0, stream>>>(bsum, bofs);
        scatter_k<<<NBLK_E, 256, 0, stream>>>(ei, loc, bofs, rank, eids, dsts);
        edge_csr <<<NBLK_E, 256, 0, stream>>>(x, ei, ea, w1, b1, w2, b2, eids, dsts, sums);
        finalize_sums<<<NBLK_N, 256, 0, stream>>>(x, root, bias, sums, deg, out);
    }
}